// Round 1
// baseline (323.945 us; speedup 1.0000x reference)
//
#include <hip/hip_runtime.h>
#include <hip/hip_fp16.h>

#define N_NODES 50000
#define N_EDGES 1600000
#define F_IN 8
#define F_OUT 12
#define PERIODS 6
#define FP 48                      // F_IN * PERIODS
#define DEG_CAP 96                 // per-node CSR capacity (mean 32, ~11 sigma; safety cap only)

// ---- pass 0: init per-node cursor=0, deg=1.0 (self loop weight) ----
__global__ void k_init(unsigned int* __restrict__ cursor, float* __restrict__ deg) {
    int t = blockIdx.x * blockDim.x + threadIdx.x;
    if (t < N_NODES) { cursor[t] = 0u; deg[t] = 1.0f; }
}

// ---- pass 1: direct-placement CSR build (one pass, no sort) ----
// entry: (fp16(ew) << 16) | src   (src < 50000 < 2^16)
__global__ void __launch_bounds__(256) k_scatter(const int4* __restrict__ src4,
                                                 const int4* __restrict__ dst4,
                                                 const float4* __restrict__ ew4,
                                                 unsigned int* __restrict__ cursor,
                                                 float* __restrict__ deg,
                                                 unsigned int* __restrict__ csr4) {
    int t = blockIdx.x * 256 + threadIdx.x;
    if (t >= N_EDGES / 4) return;
    int4 ss = src4[t];
    int4 dd = dst4[t];
    float4 ww = ew4[t];
    int s[4] = { ss.x, ss.y, ss.z, ss.w };
    int d[4] = { dd.x, dd.y, dd.z, dd.w };
    float w[4] = { ww.x, ww.y, ww.z, ww.w };
    #pragma unroll
    for (int u = 0; u < 4; u++) {
        unsigned int pos = atomicAdd(&cursor[d[u]], 1u);
        atomicAdd(&deg[d[u]], w[u]);           // full fp32 weight for degree
        if (pos < DEG_CAP) {                   // memory safety only
            __half hw = __float2half(w[u]);
            csr4[(size_t)d[u] * DEG_CAP + pos] =
                ((unsigned int)__half_as_ushort(hw) << 16) | (unsigned int)s[u];
        }
    }
}

// ---- pass 2: dinv + scaled fp16 features, xs[n][c] = fp16(dinv[n]*x[n, 8c..8c+7]) ----
__global__ void __launch_bounds__(256) k_xs(const float* __restrict__ x,
                                            const float* __restrict__ deg,
                                            float* __restrict__ dinv,
                                            uint4* __restrict__ xs) {
    int t = blockIdx.x * 256 + threadIdx.x;
    if (t >= N_NODES * 6) return;
    int n = t / 6, c = t % 6;
    float di = rsqrtf(deg[n]);                 // deg >= 1 always
    if (c == 0) dinv[n] = di;
    const float4* xr = (const float4*)(x + (size_t)n * FP + c * 8);
    float4 a = xr[0], b = xr[1];
    __half2 h0 = __floats2half2_rn(di * a.x, di * a.y);
    __half2 h1 = __floats2half2_rn(di * a.z, di * a.w);
    __half2 h2 = __floats2half2_rn(di * b.x, di * b.y);
    __half2 h3 = __floats2half2_rn(di * b.z, di * b.w);
    uint4 o;
    o.x = *(unsigned int*)&h0; o.y = *(unsigned int*)&h1;
    o.z = *(unsigned int*)&h2; o.w = *(unsigned int*)&h3;
    xs[t] = o;
}

// ---- pass 3: gather. 12 lanes/node = 6 feature-chunks x 2 edge-groups ----
// Each lane walks edges {g, g+2, ...} of its node with 16B uint4 gathers,
// pair (t, t^1) combined with one shfl_xor. Halves the dependent chain.
__global__ void __launch_bounds__(256) k_gather(const uint4* __restrict__ xs,
                                                const float* __restrict__ dinv,
                                                const unsigned int* __restrict__ cursor,
                                                const unsigned int* __restrict__ csr4,
                                                uint4* __restrict__ xagg) {
    int t = blockIdx.x * 256 + threadIdx.x;
    if (t >= N_NODES * 12) return;
    int n = t / 12, r = t % 12, c = r >> 1, g = r & 1;
    unsigned int cnt = cursor[n];
    if (cnt > DEG_CAP) cnt = DEG_CAP;
    const unsigned int* row = csr4 + (size_t)n * DEG_CAP;
    float a0 = 0.f, a1 = 0.f, a2 = 0.f, a3 = 0.f;
    float a4 = 0.f, a5 = 0.f, a6 = 0.f, a7 = 0.f;
    int kk = 0;
    for (; kk + 8 <= (int)cnt; kk += 8) {
        unsigned int p[4]; uint4 v[4];
        #pragma unroll
        for (int u = 0; u < 4; u++) p[u] = row[kk + 2 * u + g];
        #pragma unroll
        for (int u = 0; u < 4; u++)
            v[u] = xs[(size_t)(p[u] & 0xFFFFu) * 6 + c];
        #pragma unroll
        for (int u = 0; u < 4; u++) {
            float w = __half2float(__ushort_as_half((unsigned short)(p[u] >> 16)));
            float2 e0 = __half22float2(*(__half2*)&v[u].x);
            float2 e1 = __half22float2(*(__half2*)&v[u].y);
            float2 e2 = __half22float2(*(__half2*)&v[u].z);
            float2 e3 = __half22float2(*(__half2*)&v[u].w);
            a0 += w * e0.x; a1 += w * e0.y; a2 += w * e1.x; a3 += w * e1.y;
            a4 += w * e2.x; a5 += w * e2.y; a6 += w * e3.x; a7 += w * e3.y;
        }
    }
    for (int j = kk + g; j < (int)cnt; j += 2) {
        unsigned int p = row[j];
        float w = __half2float(__ushort_as_half((unsigned short)(p >> 16)));
        uint4 v = xs[(size_t)(p & 0xFFFFu) * 6 + c];
        float2 e0 = __half22float2(*(__half2*)&v.x);
        float2 e1 = __half22float2(*(__half2*)&v.y);
        float2 e2 = __half22float2(*(__half2*)&v.z);
        float2 e3 = __half22float2(*(__half2*)&v.w);
        a0 += w * e0.x; a1 += w * e0.y; a2 += w * e1.x; a3 += w * e1.y;
        a4 += w * e2.x; a5 += w * e2.y; a6 += w * e3.x; a7 += w * e3.y;
    }
    // combine the two edge-groups (partner = t^1, always same wave, same node)
    a0 += __shfl_xor(a0, 1); a1 += __shfl_xor(a1, 1);
    a2 += __shfl_xor(a2, 1); a3 += __shfl_xor(a3, 1);
    a4 += __shfl_xor(a4, 1); a5 += __shfl_xor(a5, 1);
    a6 += __shfl_xor(a6, 1); a7 += __shfl_xor(a7, 1);
    if (g == 0) {
        uint4 sf = xs[(size_t)n * 6 + c];      // self loop (dinv[n]*x already folded)
        float2 s0 = __half22float2(*(__half2*)&sf.x);
        float2 s1 = __half22float2(*(__half2*)&sf.y);
        float2 s2 = __half22float2(*(__half2*)&sf.z);
        float2 s3 = __half22float2(*(__half2*)&sf.w);
        a0 += s0.x; a1 += s0.y; a2 += s1.x; a3 += s1.y;
        a4 += s2.x; a5 += s2.y; a6 += s3.x; a7 += s3.y;
        float di = dinv[n];
        __half2 h0 = __floats2half2_rn(di * a0, di * a1);
        __half2 h1 = __floats2half2_rn(di * a2, di * a3);
        __half2 h2 = __floats2half2_rn(di * a4, di * a5);
        __half2 h3 = __floats2half2_rn(di * a6, di * a7);
        uint4 o;
        o.x = *(unsigned int*)&h0; o.y = *(unsigned int*)&h1;
        o.z = *(unsigned int*)&h2; o.w = *(unsigned int*)&h3;
        xagg[(size_t)n * 6 + c] = o;
    }
}

// ---- pass 4: per-node fused epilogue (gates + attention + relu + linear) ----
// H0 == 0 => R gate dead; Z/Ht use only first F_OUT cols of lzW/lhW.
__global__ void k_node(const uint4* __restrict__ xagg, const float* __restrict__ att,
                       const float* __restrict__ Wz, const float* __restrict__ bz,
                       const float* __restrict__ Wh, const float* __restrict__ bh,
                       const float* __restrict__ lzW, const float* __restrict__ lzb,
                       const float* __restrict__ lhW, const float* __restrict__ lhb,
                       const float* __restrict__ linW, const float* __restrict__ linb,
                       float* __restrict__ out) {
    int n = blockIdx.x * blockDim.x + threadIdx.x;
    if (n >= N_NODES) return;

    float a[PERIODS];
    float m = -1e30f;
    #pragma unroll
    for (int p = 0; p < PERIODS; p++) { a[p] = att[p]; m = fmaxf(m, a[p]); }
    float se = 0.f;
    #pragma unroll
    for (int p = 0; p < PERIODS; p++) { a[p] = __expf(a[p] - m); se += a[p]; }
    float inv = 1.f / se;
    #pragma unroll
    for (int p = 0; p < PERIODS; p++) a[p] *= inv;

    float row[FP];
    const uint4* xr = xagg + (size_t)n * 6;
    #pragma unroll
    for (int i = 0; i < 6; i++) {
        uint4 v = xr[i];
        float2 f0 = __half22float2(*(__half2*)&v.x);
        float2 f1 = __half22float2(*(__half2*)&v.y);
        float2 f2 = __half22float2(*(__half2*)&v.z);
        float2 f3 = __half22float2(*(__half2*)&v.w);
        row[8 * i + 0] = f0.x; row[8 * i + 1] = f0.y;
        row[8 * i + 2] = f1.x; row[8 * i + 3] = f1.y;
        row[8 * i + 4] = f2.x; row[8 * i + 5] = f2.y;
        row[8 * i + 6] = f3.x; row[8 * i + 7] = f3.y;
    }

    float H[F_OUT];
    #pragma unroll
    for (int j = 0; j < F_OUT; j++) H[j] = 0.f;

    for (int p = 0; p < PERIODS; p++) {
        float gz[F_OUT], gh[F_OUT];
        #pragma unroll
        for (int j = 0; j < F_OUT; j++) { gz[j] = bz[j]; gh[j] = bh[j]; }
        #pragma unroll
        for (int f = 0; f < F_IN; f++) {
            float xv = row[f * PERIODS + p];
            #pragma unroll
            for (int j = 0; j < F_OUT; j++) {
                gz[j] += xv * Wz[f * F_OUT + j];
                gh[j] += xv * Wh[f * F_OUT + j];
            }
        }
        #pragma unroll
        for (int j = 0; j < F_OUT; j++) {
            float z = lzb[j], t2 = lhb[j];
            #pragma unroll
            for (int kk = 0; kk < F_OUT; kk++) {
                z  += gz[kk] * lzW[j * (2 * F_OUT) + kk];
                t2 += gh[kk] * lhW[j * (2 * F_OUT) + kk];
            }
            float Z = 1.f / (1.f + __expf(-z));
            // fast tanh: 1 - 2/(e^{2x}+1); saturates correctly for |x| large
            float e2 = __expf(2.f * t2);
            float th = 1.f - __fdividef(2.f, e2 + 1.f);
            H[j] += a[p] * (1.f - Z) * th;
        }
    }

    float* op = out + (size_t)n * PERIODS;
    #pragma unroll
    for (int q = 0; q < PERIODS; q++) {
        float acc = linb[q];
        #pragma unroll
        for (int j = 0; j < F_OUT; j++)
            acc += fmaxf(H[j], 0.f) * linW[q * F_OUT + j];
        op[q] = acc;
    }
}

extern "C" void kernel_launch(void* const* d_in, const int* in_sizes, int n_in,
                              void* d_out, int out_size, void* d_ws, size_t ws_size,
                              hipStream_t stream) {
    const float* x    = (const float*)d_in[0];
    const int*   ei   = (const int*)d_in[1];
    const float* ew   = (const float*)d_in[2];
    const float* att  = (const float*)d_in[3];
    const float* Wz   = (const float*)d_in[4];
    const float* bz   = (const float*)d_in[5];
    // d_in[6]=Wr, d_in[7]=br : dead (H0 == 0)
    const float* Wh   = (const float*)d_in[8];
    const float* bh   = (const float*)d_in[9];
    const float* lzW  = (const float*)d_in[10];
    const float* lzb  = (const float*)d_in[11];
    // d_in[12]=lrW, d_in[13]=lrb : dead
    const float* lhW  = (const float*)d_in[14];
    const float* lhb  = (const float*)d_in[15];
    const float* linW = (const float*)d_in[16];
    const float* linb = (const float*)d_in[17];
    float* out = (float*)d_out;

    // ws layout (~29.4 MB): xs, xagg (16B-aligned first), csr4, cursor, deg, dinv
    uint4* xs   = (uint4*)d_ws;                                   // N*6 uint4 = 4.8 MB
    uint4* xagg = xs + (size_t)N_NODES * 6;                       // 4.8 MB
    unsigned int* csr4 = (unsigned int*)(xagg + (size_t)N_NODES * 6); // N*96*4B = 19.2 MB
    unsigned int* cursor = csr4 + (size_t)N_NODES * DEG_CAP;      // N u32
    float* deg  = (float*)(cursor + N_NODES);                     // N f32
    float* dinv = deg + N_NODES;                                  // N f32

    const int* srcp = ei;
    const int* dstp = ei + N_EDGES;

    k_init<<<(N_NODES + 511) / 512, 512, 0, stream>>>(cursor, deg);
    k_scatter<<<(N_EDGES / 4 + 255) / 256, 256, 0, stream>>>(
        (const int4*)srcp, (const int4*)dstp, (const float4*)ew, cursor, deg, csr4);
    k_xs<<<(N_NODES * 6 + 255) / 256, 256, 0, stream>>>(x, deg, dinv, xs);
    k_gather<<<(N_NODES * 12 + 255) / 256, 256, 0, stream>>>(xs, dinv, cursor, csr4, xagg);
    k_node<<<(N_NODES + 255) / 256, 256, 0, stream>>>(xagg, att, Wz, bz, Wh, bh,
                                                      lzW, lzb, lhW, lhb, linW, linb, out);
}

// Round 2
// 252.726 us; speedup vs baseline: 1.2818x; 1.2818x over previous
//
#include <hip/hip_runtime.h>
#include <hip/hip_fp16.h>

#define N_NODES 50000
#define N_EDGES 1600000
#define F_IN 8
#define F_OUT 12
#define PERIODS 6
#define FP 48                      // F_IN * PERIODS
#define BKT_SH 7                   // 128 nodes per bucket
#define BKT_N 128
#define NBKT ((N_NODES + BKT_N - 1) / BKT_N)   // 391
#define CHK 4096                   // edges per scatter block (8/thread, int4 loads)
#define NCHK ((N_EDGES + CHK - 1) / CHK)       // 391
#define SEG_CAP 4736               // fixed per-bucket segment stride (mean 4092, +10 sigma)

// ---- pass 0: zero the 391 bucket cursors ----
__global__ void k_zero(unsigned int* __restrict__ cursor) {
    int i = threadIdx.x;
    if (i < NBKT) cursor[i] = 0u;
}

// ---- pass 1: fused histogram + reservation + scatter (bucketed; full-line writes) ----
// part entry: hi32 = fp32 ew bits, lo32 = (dlocal&127)<<24 | src   (src < 2^16)
__global__ void __launch_bounds__(512) k_scatter(const int4* __restrict__ src4,
                                                 const int4* __restrict__ dst4,
                                                 const float4* __restrict__ ew4,
                                                 unsigned int* __restrict__ cursor,
                                                 unsigned long long* __restrict__ part) {
    __shared__ unsigned int h[NBKT];
    __shared__ unsigned int gbase[NBKT];
    int tid = threadIdx.x, blk = blockIdx.x;
    for (int k = tid; k < NBKT; k += 512) h[k] = 0u;
    __syncthreads();
    int qbase = blk * (CHK / 4);                 // in units of 4-edge groups
    int bv[8]; unsigned int lr[8], lo[8], hiw[8]; bool val[8];
    #pragma unroll
    for (int u = 0; u < 2; u++) {
        int q = qbase + u * 512 + tid;
        bool v = (q < N_EDGES / 4);
        int4 ss = v ? src4[q] : make_int4(0, 0, 0, 0);
        int4 dd = v ? dst4[q] : make_int4(0, 0, 0, 0);
        float4 ww = v ? ew4[q] : make_float4(0.f, 0.f, 0.f, 0.f);
        int s[4] = { ss.x, ss.y, ss.z, ss.w };
        int d[4] = { dd.x, dd.y, dd.z, dd.w };
        float w[4] = { ww.x, ww.y, ww.z, ww.w };
        #pragma unroll
        for (int e = 0; e < 4; e++) {
            int i = u * 4 + e;
            val[i] = v;
            if (v) {
                int b = d[e] >> BKT_SH;
                bv[i] = b;
                lr[i] = atomicAdd(&h[b], 1u);
                lo[i] = ((unsigned int)(d[e] & (BKT_N - 1)) << 24) | (unsigned int)s[e];
                hiw[i] = __float_as_uint(w[e]);
            }
        }
    }
    __syncthreads();
    for (int k = tid; k < NBKT; k += 512) {
        unsigned int c = h[k];
        gbase[k] = c ? atomicAdd(&cursor[k], c) : 0u;
    }
    __syncthreads();
    #pragma unroll
    for (int i = 0; i < 8; i++) {
        if (!val[i]) continue;
        unsigned int off = gbase[bv[i]] + lr[i];
        if (off < SEG_CAP)  // 10-sigma margin; memory safety only
            __builtin_nontemporal_store(
                ((unsigned long long)hiw[i] << 32) | lo[i],
                &part[(size_t)bv[i] * SEG_CAP + off]);
    }
}

// ---- pass 2: per-bucket counting sort (rank-in-entry, no 2nd-pass atomics) ----
// Also emits deg/dinv, csr4 ((fp16 ew)<<16 | src), and xs[n][c] = fp16(dinv*x[n,8c..8c+7]).
__global__ void __launch_bounds__(512) k_bucket(const unsigned long long* __restrict__ part,
                                                const unsigned int* __restrict__ cursor,
                                                const float* __restrict__ x,
                                                int2* __restrict__ offs2,
                                                float* __restrict__ dinv_g,
                                                uint4* __restrict__ xs,
                                                unsigned int* __restrict__ csr4) {
    __shared__ uint2 stage[SEG_CAP];
    __shared__ unsigned int cnt[BKT_N], rowstart[BKT_N], sc[BKT_N];
    __shared__ float degf[BKT_N], dinv_l[BKT_N];
    int tid = threadIdx.x, k = blockIdx.x;
    unsigned int base = (unsigned int)k * SEG_CAP;
    unsigned int m = cursor[k];
    if (m > SEG_CAP) m = SEG_CAP;
    if (tid < BKT_N) { cnt[tid] = 0u; degf[tid] = 1.0f; }  // self loop weight
    __syncthreads();

    // histogram + rank assignment + fp32 degree
    for (unsigned int i = tid; i < m; i += 512) {
        unsigned long long p = __builtin_nontemporal_load(&part[base + i]);
        unsigned int lo = (unsigned int)p;
        unsigned int hi = (unsigned int)(p >> 32);
        unsigned int j = (lo >> 24) & (BKT_N - 1);
        unsigned int r = atomicAdd(&cnt[j], 1u);
        atomicAdd(&degf[j], __uint_as_float(hi));
        if (r > 255u) r = 255u;                 // impossible in practice; safety clamp
        stage[i] = make_uint2(lo | (r << 16), hi);   // bits[23:16] free (src < 2^16)
    }
    __syncthreads();

    // wave-0 shfl prefix scan over 128 bucket counters (inclusive)
    if (tid < 64) {
        unsigned int a = cnt[tid], b = cnt[tid + 64];
        unsigned int sa = a;
        #pragma unroll
        for (int off = 1; off < 64; off <<= 1) {
            unsigned int tv = __shfl_up(sa, off);
            if ((tid & 63) >= off) sa += tv;
        }
        unsigned int tot = __shfl(sa, 63);
        unsigned int sb = b;
        #pragma unroll
        for (int off = 1; off < 64; off <<= 1) {
            unsigned int tv = __shfl_up(sb, off);
            if ((tid & 63) >= off) sb += tv;
        }
        sc[tid] = sa;
        sc[tid + 64] = sb + tot;
    }
    __syncthreads();

    int n0 = k * BKT_N;
    int nn = N_NODES - n0; if (nn > BKT_N) nn = BKT_N;

    if (tid < BKT_N) {
        unsigned int rs = sc[tid] - cnt[tid];
        rowstart[tid] = rs;
        float dv = rsqrtf(degf[tid]);
        dinv_l[tid] = dv;
        if (tid < nn) {
            dinv_g[n0 + tid] = dv;
            offs2[n0 + tid] = make_int2((int)(base + rs), (int)(base + sc[tid]));
        }
    }
    __syncthreads();

    // sorted write-out: slot = rowstart[j] + stored rank (no atomics)
    for (unsigned int i = tid; i < m; i += 512) {
        uint2 vv = stage[i];
        unsigned int j = (vv.x >> 24) & (BKT_N - 1);
        unsigned int r = (vv.x >> 16) & 0xFFu;
        __half hw = __float2half(__uint_as_float(vv.y));
        unsigned int entry = ((unsigned int)__half_as_ushort(hw) << 16) |
                             (vv.x & 0xFFFFu);
        csr4[base + rowstart[j] + r] = entry;
    }

    // xs[n*6+c] = fp16(dinv[n] * x[n, 8c..8c+7])  (coalesced uint4)
    for (int idx = tid; idx < nn * 6; idx += 512) {
        int j = idx / 6, c = idx % 6;
        float di = dinv_l[j];
        const float4* xr = (const float4*)(x + (size_t)(n0 + j) * FP + c * 8);
        float4 a = xr[0], b = xr[1];
        __half2 h0 = __floats2half2_rn(di * a.x, di * a.y);
        __half2 h1 = __floats2half2_rn(di * a.z, di * a.w);
        __half2 h2 = __floats2half2_rn(di * b.x, di * b.y);
        __half2 h3 = __floats2half2_rn(di * b.z, di * b.w);
        uint4 o;
        o.x = *(unsigned int*)&h0; o.y = *(unsigned int*)&h1;
        o.z = *(unsigned int*)&h2; o.w = *(unsigned int*)&h3;
        xs[(size_t)(n0 + j) * 6 + c] = o;
    }
}

// ---- pass 3: gather. 12 lanes/node = 6 feature-chunks x 2 edge-groups ----
// Each lane walks edges {g, g+2, ...} of its node with 16B uint4 gathers;
// pair (t, t^1) combined with one shfl_xor. NT csr loads keep xs hot in L2.
__global__ void __launch_bounds__(256) k_gather(const uint4* __restrict__ xs,
                                                const float* __restrict__ dinv,
                                                const int2* __restrict__ offs2,
                                                const unsigned int* __restrict__ csr4,
                                                uint4* __restrict__ xagg) {
    int t = blockIdx.x * 256 + threadIdx.x;
    if (t >= N_NODES * 12) return;
    int n = t / 12, r = t % 12, c = r >> 1, g = r & 1;
    int2 oe = offs2[n];
    const unsigned int* rowp = csr4 + oe.x;
    int cnt = oe.y - oe.x;
    float a0 = 0.f, a1 = 0.f, a2 = 0.f, a3 = 0.f;
    float a4 = 0.f, a5 = 0.f, a6 = 0.f, a7 = 0.f;
    int kk = 0;
    for (; kk + 8 <= cnt; kk += 8) {
        unsigned int p[4]; uint4 v[4];
        #pragma unroll
        for (int u = 0; u < 4; u++)
            p[u] = __builtin_nontemporal_load(rowp + kk + 2 * u + g);
        #pragma unroll
        for (int u = 0; u < 4; u++)
            v[u] = xs[(size_t)(p[u] & 0xFFFFu) * 6 + c];
        #pragma unroll
        for (int u = 0; u < 4; u++) {
            float w = __half2float(__ushort_as_half((unsigned short)(p[u] >> 16)));
            float2 e0 = __half22float2(*(__half2*)&v[u].x);
            float2 e1 = __half22float2(*(__half2*)&v[u].y);
            float2 e2 = __half22float2(*(__half2*)&v[u].z);
            float2 e3 = __half22float2(*(__half2*)&v[u].w);
            a0 += w * e0.x; a1 += w * e0.y; a2 += w * e1.x; a3 += w * e1.y;
            a4 += w * e2.x; a5 += w * e2.y; a6 += w * e3.x; a7 += w * e3.y;
        }
    }
    for (int j = kk + g; j < cnt; j += 2) {
        unsigned int p = __builtin_nontemporal_load(rowp + j);
        float w = __half2float(__ushort_as_half((unsigned short)(p >> 16)));
        uint4 v = xs[(size_t)(p & 0xFFFFu) * 6 + c];
        float2 e0 = __half22float2(*(__half2*)&v.x);
        float2 e1 = __half22float2(*(__half2*)&v.y);
        float2 e2 = __half22float2(*(__half2*)&v.z);
        float2 e3 = __half22float2(*(__half2*)&v.w);
        a0 += w * e0.x; a1 += w * e0.y; a2 += w * e1.x; a3 += w * e1.y;
        a4 += w * e2.x; a5 += w * e2.y; a6 += w * e3.x; a7 += w * e3.y;
    }
    // combine the two edge-groups (partner = t^1, same wave, same node, same c)
    a0 += __shfl_xor(a0, 1); a1 += __shfl_xor(a1, 1);
    a2 += __shfl_xor(a2, 1); a3 += __shfl_xor(a3, 1);
    a4 += __shfl_xor(a4, 1); a5 += __shfl_xor(a5, 1);
    a6 += __shfl_xor(a6, 1); a7 += __shfl_xor(a7, 1);
    if (g == 0) {
        uint4 sf = xs[(size_t)n * 6 + c];      // self loop (dinv[n]*x already folded)
        float2 s0 = __half22float2(*(__half2*)&sf.x);
        float2 s1 = __half22float2(*(__half2*)&sf.y);
        float2 s2 = __half22float2(*(__half2*)&sf.z);
        float2 s3 = __half22float2(*(__half2*)&sf.w);
        a0 += s0.x; a1 += s0.y; a2 += s1.x; a3 += s1.y;
        a4 += s2.x; a5 += s2.y; a6 += s3.x; a7 += s3.y;
        float di = dinv[n];
        __half2 h0 = __floats2half2_rn(di * a0, di * a1);
        __half2 h1 = __floats2half2_rn(di * a2, di * a3);
        __half2 h2 = __floats2half2_rn(di * a4, di * a5);
        __half2 h3 = __floats2half2_rn(di * a6, di * a7);
        uint4 o;
        o.x = *(unsigned int*)&h0; o.y = *(unsigned int*)&h1;
        o.z = *(unsigned int*)&h2; o.w = *(unsigned int*)&h3;
        xagg[(size_t)n * 6 + c] = o;
    }
}

// ---- pass 4: per-node fused epilogue (gates + attention + relu + linear) ----
// H0 == 0 => R gate dead; Z/Ht use only first F_OUT cols of lzW/lhW.
__global__ void k_node(const uint4* __restrict__ xagg, const float* __restrict__ att,
                       const float* __restrict__ Wz, const float* __restrict__ bz,
                       const float* __restrict__ Wh, const float* __restrict__ bh,
                       const float* __restrict__ lzW, const float* __restrict__ lzb,
                       const float* __restrict__ lhW, const float* __restrict__ lhb,
                       const float* __restrict__ linW, const float* __restrict__ linb,
                       float* __restrict__ out) {
    int n = blockIdx.x * blockDim.x + threadIdx.x;
    if (n >= N_NODES) return;

    float a[PERIODS];
    float m = -1e30f;
    #pragma unroll
    for (int p = 0; p < PERIODS; p++) { a[p] = att[p]; m = fmaxf(m, a[p]); }
    float se = 0.f;
    #pragma unroll
    for (int p = 0; p < PERIODS; p++) { a[p] = __expf(a[p] - m); se += a[p]; }
    float inv = 1.f / se;
    #pragma unroll
    for (int p = 0; p < PERIODS; p++) a[p] *= inv;

    float row[FP];
    const uint4* xr = xagg + (size_t)n * 6;
    #pragma unroll
    for (int i = 0; i < 6; i++) {
        uint4 v = xr[i];
        float2 f0 = __half22float2(*(__half2*)&v.x);
        float2 f1 = __half22float2(*(__half2*)&v.y);
        float2 f2 = __half22float2(*(__half2*)&v.z);
        float2 f3 = __half22float2(*(__half2*)&v.w);
        row[8 * i + 0] = f0.x; row[8 * i + 1] = f0.y;
        row[8 * i + 2] = f1.x; row[8 * i + 3] = f1.y;
        row[8 * i + 4] = f2.x; row[8 * i + 5] = f2.y;
        row[8 * i + 6] = f3.x; row[8 * i + 7] = f3.y;
    }

    float H[F_OUT];
    #pragma unroll
    for (int j = 0; j < F_OUT; j++) H[j] = 0.f;

    for (int p = 0; p < PERIODS; p++) {
        float gz[F_OUT], gh[F_OUT];
        #pragma unroll
        for (int j = 0; j < F_OUT; j++) { gz[j] = bz[j]; gh[j] = bh[j]; }
        #pragma unroll
        for (int f = 0; f < F_IN; f++) {
            float xv = row[f * PERIODS + p];
            #pragma unroll
            for (int j = 0; j < F_OUT; j++) {
                gz[j] += xv * Wz[f * F_OUT + j];
                gh[j] += xv * Wh[f * F_OUT + j];
            }
        }
        #pragma unroll
        for (int j = 0; j < F_OUT; j++) {
            float z = lzb[j], t2 = lhb[j];
            #pragma unroll
            for (int kk = 0; kk < F_OUT; kk++) {
                z  += gz[kk] * lzW[j * (2 * F_OUT) + kk];
                t2 += gh[kk] * lhW[j * (2 * F_OUT) + kk];
            }
            float Z = 1.f / (1.f + __expf(-z));
            // fast tanh: 1 - 2/(e^{2x}+1); saturates correctly for |x| large
            float e2 = __expf(2.f * t2);
            float th = 1.f - __fdividef(2.f, e2 + 1.f);
            H[j] += a[p] * (1.f - Z) * th;
        }
    }

    float* op = out + (size_t)n * PERIODS;
    #pragma unroll
    for (int q = 0; q < PERIODS; q++) {
        float acc = linb[q];
        #pragma unroll
        for (int j = 0; j < F_OUT; j++)
            acc += fmaxf(H[j], 0.f) * linW[q * F_OUT + j];
        op[q] = acc;
    }
}

extern "C" void kernel_launch(void* const* d_in, const int* in_sizes, int n_in,
                              void* d_out, int out_size, void* d_ws, size_t ws_size,
                              hipStream_t stream) {
    const float* x    = (const float*)d_in[0];
    const int*   ei   = (const int*)d_in[1];
    const float* ew   = (const float*)d_in[2];
    const float* att  = (const float*)d_in[3];
    const float* Wz   = (const float*)d_in[4];
    const float* bz   = (const float*)d_in[5];
    // d_in[6]=Wr, d_in[7]=br : dead (H0 == 0)
    const float* Wh   = (const float*)d_in[8];
    const float* bh   = (const float*)d_in[9];
    const float* lzW  = (const float*)d_in[10];
    const float* lzb  = (const float*)d_in[11];
    // d_in[12]=lrW, d_in[13]=lrb : dead
    const float* lhW  = (const float*)d_in[14];
    const float* lhb  = (const float*)d_in[15];
    const float* linW = (const float*)d_in[16];
    const float* linb = (const float*)d_in[17];
    float* out = (float*)d_out;

    // ws layout (~32.5 MB): xs, xagg (16B-aligned first), part, csr4, offs2, dinv, cursor
    uint4* xs   = (uint4*)d_ws;                                   // N*6 uint4 = 4.8 MB
    uint4* xagg = xs + (size_t)N_NODES * 6;                       // 4.8 MB
    unsigned long long* part = (unsigned long long*)(xagg + (size_t)N_NODES * 6); // 14.8 MB
    unsigned int* csr4 = (unsigned int*)(part + (size_t)NBKT * SEG_CAP);          // 7.4 MB
    int2*  offs2 = (int2*)(csr4 + (size_t)NBKT * SEG_CAP);        // N int2
    float* dinv  = (float*)(offs2 + N_NODES);                     // N f32
    unsigned int* cursor = (unsigned int*)(dinv + N_NODES);       // NBKT u32

    const int* srcp = ei;
    const int* dstp = ei + N_EDGES;

    k_zero<<<1, 512, 0, stream>>>(cursor);
    k_scatter<<<NCHK, 512, 0, stream>>>((const int4*)srcp, (const int4*)dstp,
                                        (const float4*)ew, cursor, part);
    k_bucket<<<NBKT, 512, 0, stream>>>(part, cursor, x, offs2, dinv, xs, csr4);
    k_gather<<<(N_NODES * 12 + 255) / 256, 256, 0, stream>>>(xs, dinv, offs2, csr4, xagg);
    k_node<<<(N_NODES + 255) / 256, 256, 0, stream>>>(xagg, att, Wz, bz, Wh, bh,
                                                      lzW, lzb, lhW, lhb, linW, linb, out);
}

// Round 3
// 208.498 us; speedup vs baseline: 1.5537x; 1.2121x over previous
//
#include <hip/hip_runtime.h>
#include <hip/hip_fp16.h>

#define N_NODES 50000
#define N_EDGES 1600000
#define F_IN 8
#define F_OUT 12
#define PERIODS 6
#define FP 48                      // F_IN * PERIODS
#define BKT_SH 7                   // 128 nodes per bucket
#define BKT_N 128
#define NBKT ((N_NODES + BKT_N - 1) / BKT_N)   // 391
#define CHK 4096                   // edges per scatter block (8/thread, int4 loads)
#define NCHK ((N_EDGES + CHK - 1) / CHK)       // 391
#define SEG_CAP 4736               // fixed per-bucket segment stride (mean 4092, +10 sigma)

// ---- pass 0: zero the 391 bucket cursors ----
__global__ void k_zero(unsigned int* __restrict__ cursor) {
    int i = threadIdx.x;
    if (i < NBKT) cursor[i] = 0u;
}

// ---- pass 1: fused histogram + reservation + scatter (bucketed) ----
// part entry: hi32 = fp32 ew bits, lo32 = (dlocal&127)<<24 | src   (src < 2^16)
// PLAIN stores: per-(block,bucket) runs are contiguous, write-back L2 assembles
// full 64B lines. (NT stores here cost 6.5x write amplification — round-2 lesson.)
__global__ void __launch_bounds__(512) k_scatter(const int4* __restrict__ src4,
                                                 const int4* __restrict__ dst4,
                                                 const float4* __restrict__ ew4,
                                                 unsigned int* __restrict__ cursor,
                                                 unsigned long long* __restrict__ part) {
    __shared__ unsigned int h[NBKT];
    __shared__ unsigned int gbase[NBKT];
    int tid = threadIdx.x, blk = blockIdx.x;
    for (int k = tid; k < NBKT; k += 512) h[k] = 0u;
    __syncthreads();
    int qbase = blk * (CHK / 4);                 // in units of 4-edge groups
    int bv[8]; unsigned int lr[8], lo[8], hiw[8]; bool val[8];
    #pragma unroll
    for (int u = 0; u < 2; u++) {
        int q = qbase + u * 512 + tid;
        bool v = (q < N_EDGES / 4);
        int4 ss = v ? src4[q] : make_int4(0, 0, 0, 0);
        int4 dd = v ? dst4[q] : make_int4(0, 0, 0, 0);
        float4 ww = v ? ew4[q] : make_float4(0.f, 0.f, 0.f, 0.f);
        int s[4] = { ss.x, ss.y, ss.z, ss.w };
        int d[4] = { dd.x, dd.y, dd.z, dd.w };
        float w[4] = { ww.x, ww.y, ww.z, ww.w };
        #pragma unroll
        for (int e = 0; e < 4; e++) {
            int i = u * 4 + e;
            val[i] = v;
            if (v) {
                int b = d[e] >> BKT_SH;
                bv[i] = b;
                lr[i] = atomicAdd(&h[b], 1u);
                lo[i] = ((unsigned int)(d[e] & (BKT_N - 1)) << 24) | (unsigned int)s[e];
                hiw[i] = __float_as_uint(w[e]);
            }
        }
    }
    __syncthreads();
    for (int k = tid; k < NBKT; k += 512) {
        unsigned int c = h[k];
        gbase[k] = c ? atomicAdd(&cursor[k], c) : 0u;
    }
    __syncthreads();
    #pragma unroll
    for (int i = 0; i < 8; i++) {
        if (!val[i]) continue;
        unsigned int off = gbase[bv[i]] + lr[i];
        if (off < SEG_CAP)  // 10-sigma margin; memory safety only
            part[(size_t)bv[i] * SEG_CAP + off] =
                ((unsigned long long)hiw[i] << 32) | lo[i];
    }
}

// ---- pass 2: per-bucket counting sort (rank-in-entry, no 2nd-pass atomics) ----
// Also emits deg/dinv, csr4 ((fp16 ew)<<16 | src), and xs[n][c] = fp16(dinv*x[n,8c..8c+7]).
__global__ void __launch_bounds__(512) k_bucket(const unsigned long long* __restrict__ part,
                                                const unsigned int* __restrict__ cursor,
                                                const float* __restrict__ x,
                                                int2* __restrict__ offs2,
                                                float* __restrict__ dinv_g,
                                                uint4* __restrict__ xs,
                                                unsigned int* __restrict__ csr4) {
    __shared__ uint2 stage[SEG_CAP];
    __shared__ unsigned int cnt[BKT_N], rowstart[BKT_N], sc[BKT_N];
    __shared__ float degf[BKT_N], dinv_l[BKT_N];
    int tid = threadIdx.x, k = blockIdx.x;
    unsigned int base = (unsigned int)k * SEG_CAP;
    unsigned int m = cursor[k];
    if (m > SEG_CAP) m = SEG_CAP;
    if (tid < BKT_N) { cnt[tid] = 0u; degf[tid] = 1.0f; }  // self loop weight
    __syncthreads();

    // histogram + rank assignment + fp32 degree
    for (unsigned int i = tid; i < m; i += 512) {
        unsigned long long p = __builtin_nontemporal_load(&part[base + i]);
        unsigned int lo = (unsigned int)p;
        unsigned int hi = (unsigned int)(p >> 32);
        unsigned int j = (lo >> 24) & (BKT_N - 1);
        unsigned int r = atomicAdd(&cnt[j], 1u);
        atomicAdd(&degf[j], __uint_as_float(hi));
        if (r > 255u) r = 255u;                 // impossible in practice; safety clamp
        stage[i] = make_uint2(lo | (r << 16), hi);   // bits[23:16] free (src < 2^16)
    }
    __syncthreads();

    // wave-0 shfl prefix scan over 128 bucket counters (inclusive)
    if (tid < 64) {
        unsigned int a = cnt[tid], b = cnt[tid + 64];
        unsigned int sa = a;
        #pragma unroll
        for (int off = 1; off < 64; off <<= 1) {
            unsigned int tv = __shfl_up(sa, off);
            if ((tid & 63) >= off) sa += tv;
        }
        unsigned int tot = __shfl(sa, 63);
        unsigned int sb = b;
        #pragma unroll
        for (int off = 1; off < 64; off <<= 1) {
            unsigned int tv = __shfl_up(sb, off);
            if ((tid & 63) >= off) sb += tv;
        }
        sc[tid] = sa;
        sc[tid + 64] = sb + tot;
    }
    __syncthreads();

    int n0 = k * BKT_N;
    int nn = N_NODES - n0; if (nn > BKT_N) nn = BKT_N;

    if (tid < BKT_N) {
        unsigned int rs = sc[tid] - cnt[tid];
        rowstart[tid] = rs;
        float dv = rsqrtf(degf[tid]);
        dinv_l[tid] = dv;
        if (tid < nn) {
            dinv_g[n0 + tid] = dv;
            offs2[n0 + tid] = make_int2((int)(base + rs), (int)(base + sc[tid]));
        }
    }
    __syncthreads();

    // sorted write-out: slot = rowstart[j] + stored rank (no atomics)
    for (unsigned int i = tid; i < m; i += 512) {
        uint2 vv = stage[i];
        unsigned int j = (vv.x >> 24) & (BKT_N - 1);
        unsigned int r = (vv.x >> 16) & 0xFFu;
        __half hw = __float2half(__uint_as_float(vv.y));
        unsigned int entry = ((unsigned int)__half_as_ushort(hw) << 16) |
                             (vv.x & 0xFFFFu);
        csr4[base + rowstart[j] + r] = entry;
    }

    // xs[n*6+c] = fp16(dinv[n] * x[n, 8c..8c+7])  (coalesced uint4)
    for (int idx = tid; idx < nn * 6; idx += 512) {
        int j = idx / 6, c = idx % 6;
        float di = dinv_l[j];
        const float4* xr = (const float4*)(x + (size_t)(n0 + j) * FP + c * 8);
        float4 a = xr[0], b = xr[1];
        __half2 h0 = __floats2half2_rn(di * a.x, di * a.y);
        __half2 h1 = __floats2half2_rn(di * a.z, di * a.w);
        __half2 h2 = __floats2half2_rn(di * b.x, di * b.y);
        __half2 h3 = __floats2half2_rn(di * b.z, di * b.w);
        uint4 o;
        o.x = *(unsigned int*)&h0; o.y = *(unsigned int*)&h1;
        o.z = *(unsigned int*)&h2; o.w = *(unsigned int*)&h3;
        xs[(size_t)(n0 + j) * 6 + c] = o;
    }
}

// ---- pass 3: gather. 24 lanes/node = 6 feature-chunks x 4 edge-groups ----
// Each group-lane walks edges {g, g+4, ...}: dependent-chain length = deg/4.
// Lane 4-blocks (t&~3) are same (node,chunk), never straddle a wave ->
// combine with shfl_xor 1 then 2. NT csr loads keep xs hot in L2.
__global__ void __launch_bounds__(256) k_gather(const uint4* __restrict__ xs,
                                                const float* __restrict__ dinv,
                                                const int2* __restrict__ offs2,
                                                const unsigned int* __restrict__ csr4,
                                                uint4* __restrict__ xagg) {
    int t = blockIdx.x * 256 + threadIdx.x;
    if (t >= N_NODES * 24) return;
    int n = t / 24, r = t % 24, c = r >> 2, g = r & 3;
    int2 oe = offs2[n];
    const unsigned int* rowp = csr4 + oe.x;
    int cnt = oe.y - oe.x;
    float a0 = 0.f, a1 = 0.f, a2 = 0.f, a3 = 0.f;
    float a4 = 0.f, a5 = 0.f, a6 = 0.f, a7 = 0.f;
    int kk = 0;
    for (; kk + 16 <= cnt; kk += 16) {
        unsigned int p[4]; uint4 v[4];
        #pragma unroll
        for (int u = 0; u < 4; u++)
            p[u] = __builtin_nontemporal_load(rowp + kk + 4 * u + g);
        #pragma unroll
        for (int u = 0; u < 4; u++)
            v[u] = xs[(size_t)(p[u] & 0xFFFFu) * 6 + c];
        #pragma unroll
        for (int u = 0; u < 4; u++) {
            float w = __half2float(__ushort_as_half((unsigned short)(p[u] >> 16)));
            float2 e0 = __half22float2(*(__half2*)&v[u].x);
            float2 e1 = __half22float2(*(__half2*)&v[u].y);
            float2 e2 = __half22float2(*(__half2*)&v[u].z);
            float2 e3 = __half22float2(*(__half2*)&v[u].w);
            a0 += w * e0.x; a1 += w * e0.y; a2 += w * e1.x; a3 += w * e1.y;
            a4 += w * e2.x; a5 += w * e2.y; a6 += w * e3.x; a7 += w * e3.y;
        }
    }
    for (int j = kk + g; j < cnt; j += 4) {
        unsigned int p = __builtin_nontemporal_load(rowp + j);
        float w = __half2float(__ushort_as_half((unsigned short)(p >> 16)));
        uint4 v = xs[(size_t)(p & 0xFFFFu) * 6 + c];
        float2 e0 = __half22float2(*(__half2*)&v.x);
        float2 e1 = __half22float2(*(__half2*)&v.y);
        float2 e2 = __half22float2(*(__half2*)&v.z);
        float2 e3 = __half22float2(*(__half2*)&v.w);
        a0 += w * e0.x; a1 += w * e0.y; a2 += w * e1.x; a3 += w * e1.y;
        a4 += w * e2.x; a5 += w * e2.y; a6 += w * e3.x; a7 += w * e3.y;
    }
    // combine the 4 edge-groups (partners t^1, t^2: same wave, same node/chunk)
    a0 += __shfl_xor(a0, 1); a1 += __shfl_xor(a1, 1);
    a2 += __shfl_xor(a2, 1); a3 += __shfl_xor(a3, 1);
    a4 += __shfl_xor(a4, 1); a5 += __shfl_xor(a5, 1);
    a6 += __shfl_xor(a6, 1); a7 += __shfl_xor(a7, 1);
    a0 += __shfl_xor(a0, 2); a1 += __shfl_xor(a1, 2);
    a2 += __shfl_xor(a2, 2); a3 += __shfl_xor(a3, 2);
    a4 += __shfl_xor(a4, 2); a5 += __shfl_xor(a5, 2);
    a6 += __shfl_xor(a6, 2); a7 += __shfl_xor(a7, 2);
    if (g == 0) {
        uint4 sf = xs[(size_t)n * 6 + c];      // self loop (dinv[n]*x already folded)
        float2 s0 = __half22float2(*(__half2*)&sf.x);
        float2 s1 = __half22float2(*(__half2*)&sf.y);
        float2 s2 = __half22float2(*(__half2*)&sf.z);
        float2 s3 = __half22float2(*(__half2*)&sf.w);
        a0 += s0.x; a1 += s0.y; a2 += s1.x; a3 += s1.y;
        a4 += s2.x; a5 += s2.y; a6 += s3.x; a7 += s3.y;
        float di = dinv[n];
        __half2 h0 = __floats2half2_rn(di * a0, di * a1);
        __half2 h1 = __floats2half2_rn(di * a2, di * a3);
        __half2 h2 = __floats2half2_rn(di * a4, di * a5);
        __half2 h3 = __floats2half2_rn(di * a6, di * a7);
        uint4 o;
        o.x = *(unsigned int*)&h0; o.y = *(unsigned int*)&h1;
        o.z = *(unsigned int*)&h2; o.w = *(unsigned int*)&h3;
        xagg[(size_t)n * 6 + c] = o;
    }
}

// ---- pass 4: per-node fused epilogue (gates + attention + relu + linear) ----
// H0 == 0 => R gate dead; Z/Ht use only first F_OUT cols of lzW/lhW.
__global__ void k_node(const uint4* __restrict__ xagg, const float* __restrict__ att,
                       const float* __restrict__ Wz, const float* __restrict__ bz,
                       const float* __restrict__ Wh, const float* __restrict__ bh,
                       const float* __restrict__ lzW, const float* __restrict__ lzb,
                       const float* __restrict__ lhW, const float* __restrict__ lhb,
                       const float* __restrict__ linW, const float* __restrict__ linb,
                       float* __restrict__ out) {
    int n = blockIdx.x * blockDim.x + threadIdx.x;
    if (n >= N_NODES) return;

    float a[PERIODS];
    float m = -1e30f;
    #pragma unroll
    for (int p = 0; p < PERIODS; p++) { a[p] = att[p]; m = fmaxf(m, a[p]); }
    float se = 0.f;
    #pragma unroll
    for (int p = 0; p < PERIODS; p++) { a[p] = __expf(a[p] - m); se += a[p]; }
    float inv = 1.f / se;
    #pragma unroll
    for (int p = 0; p < PERIODS; p++) a[p] *= inv;

    float row[FP];
    const uint4* xr = xagg + (size_t)n * 6;
    #pragma unroll
    for (int i = 0; i < 6; i++) {
        uint4 v = xr[i];
        float2 f0 = __half22float2(*(__half2*)&v.x);
        float2 f1 = __half22float2(*(__half2*)&v.y);
        float2 f2 = __half22float2(*(__half2*)&v.z);
        float2 f3 = __half22float2(*(__half2*)&v.w);
        row[8 * i + 0] = f0.x; row[8 * i + 1] = f0.y;
        row[8 * i + 2] = f1.x; row[8 * i + 3] = f1.y;
        row[8 * i + 4] = f2.x; row[8 * i + 5] = f2.y;
        row[8 * i + 6] = f3.x; row[8 * i + 7] = f3.y;
    }

    float H[F_OUT];
    #pragma unroll
    for (int j = 0; j < F_OUT; j++) H[j] = 0.f;

    for (int p = 0; p < PERIODS; p++) {
        float gz[F_OUT], gh[F_OUT];
        #pragma unroll
        for (int j = 0; j < F_OUT; j++) { gz[j] = bz[j]; gh[j] = bh[j]; }
        #pragma unroll
        for (int f = 0; f < F_IN; f++) {
            float xv = row[f * PERIODS + p];
            #pragma unroll
            for (int j = 0; j < F_OUT; j++) {
                gz[j] += xv * Wz[f * F_OUT + j];
                gh[j] += xv * Wh[f * F_OUT + j];
            }
        }
        #pragma unroll
        for (int j = 0; j < F_OUT; j++) {
            float z = lzb[j], t2 = lhb[j];
            #pragma unroll
            for (int kk = 0; kk < F_OUT; kk++) {
                z  += gz[kk] * lzW[j * (2 * F_OUT) + kk];
                t2 += gh[kk] * lhW[j * (2 * F_OUT) + kk];
            }
            float Z = 1.f / (1.f + __expf(-z));
            // fast tanh: 1 - 2/(e^{2x}+1); saturates correctly for |x| large
            float e2 = __expf(2.f * t2);
            float th = 1.f - __fdividef(2.f, e2 + 1.f);
            H[j] += a[p] * (1.f - Z) * th;
        }
    }

    float* op = out + (size_t)n * PERIODS;
    #pragma unroll
    for (int q = 0; q < PERIODS; q++) {
        float acc = linb[q];
        #pragma unroll
        for (int j = 0; j < F_OUT; j++)
            acc += fmaxf(H[j], 0.f) * linW[q * F_OUT + j];
        op[q] = acc;
    }
}

extern "C" void kernel_launch(void* const* d_in, const int* in_sizes, int n_in,
                              void* d_out, int out_size, void* d_ws, size_t ws_size,
                              hipStream_t stream) {
    const float* x    = (const float*)d_in[0];
    const int*   ei   = (const int*)d_in[1];
    const float* ew   = (const float*)d_in[2];
    const float* att  = (const float*)d_in[3];
    const float* Wz   = (const float*)d_in[4];
    const float* bz   = (const float*)d_in[5];
    // d_in[6]=Wr, d_in[7]=br : dead (H0 == 0)
    const float* Wh   = (const float*)d_in[8];
    const float* bh   = (const float*)d_in[9];
    const float* lzW  = (const float*)d_in[10];
    const float* lzb  = (const float*)d_in[11];
    // d_in[12]=lrW, d_in[13]=lrb : dead
    const float* lhW  = (const float*)d_in[14];
    const float* lhb  = (const float*)d_in[15];
    const float* linW = (const float*)d_in[16];
    const float* linb = (const float*)d_in[17];
    float* out = (float*)d_out;

    // ws layout (~32.5 MB): xs, xagg (16B-aligned first), part, csr4, offs2, dinv, cursor
    uint4* xs   = (uint4*)d_ws;                                   // N*6 uint4 = 4.8 MB
    uint4* xagg = xs + (size_t)N_NODES * 6;                       // 4.8 MB
    unsigned long long* part = (unsigned long long*)(xagg + (size_t)N_NODES * 6); // 14.8 MB
    unsigned int* csr4 = (unsigned int*)(part + (size_t)NBKT * SEG_CAP);          // 7.4 MB
    int2*  offs2 = (int2*)(csr4 + (size_t)NBKT * SEG_CAP);        // N int2
    float* dinv  = (float*)(offs2 + N_NODES);                     // N f32
    unsigned int* cursor = (unsigned int*)(dinv + N_NODES);       // NBKT u32

    const int* srcp = ei;
    const int* dstp = ei + N_EDGES;

    k_zero<<<1, 512, 0, stream>>>(cursor);
    k_scatter<<<NCHK, 512, 0, stream>>>((const int4*)srcp, (const int4*)dstp,
                                        (const float4*)ew, cursor, part);
    k_bucket<<<NBKT, 512, 0, stream>>>(part, cursor, x, offs2, dinv, xs, csr4);
    k_gather<<<(N_NODES * 24 + 255) / 256, 256, 0, stream>>>(xs, dinv, offs2, csr4, xagg);
    k_node<<<(N_NODES + 255) / 256, 256, 0, stream>>>(xagg, att, Wz, bz, Wh, bh,
                                                      lzW, lzb, lhW, lhb, linW, linb, out);
}

// Round 4
// 187.031 us; speedup vs baseline: 1.7320x; 1.1148x over previous
//
#include <hip/hip_runtime.h>
#include <hip/hip_fp16.h>

#define N_NODES 50000
#define N_EDGES 1600000
#define F_IN 8
#define F_OUT 12
#define PERIODS 6
#define FP 48                      // F_IN * PERIODS
#define BKT_SH 7                   // 128 nodes per bucket
#define BKT_N 128
#define NBKT ((N_NODES + BKT_N - 1) / BKT_N)   // 391
#define CHK 4096                   // edges per scatter block (8/thread, int4 loads)
#define NCHK ((N_EDGES + CHK - 1) / CHK)       // 391
#define SEG_CAP 4736               // fixed per-bucket segment stride (mean 4092, +10 sigma)

// ---- pass 0: zero the 391 bucket cursors ----
__global__ void k_zero(unsigned int* __restrict__ cursor) {
    int i = threadIdx.x;
    if (i < NBKT) cursor[i] = 0u;
}

// ---- pass 1: fused histogram + reservation + scatter (bucketed) ----
// part entry: hi32 = fp32 ew bits, lo32 = (dlocal&127)<<24 | src   (src < 2^16)
// PLAIN stores: per-(block,bucket) runs are contiguous, write-back L2 assembles
// full 64B lines. (NT stores here cost 6.5x write amplification — round-2 lesson.)
__global__ void __launch_bounds__(512) k_scatter(const int4* __restrict__ src4,
                                                 const int4* __restrict__ dst4,
                                                 const float4* __restrict__ ew4,
                                                 unsigned int* __restrict__ cursor,
                                                 unsigned long long* __restrict__ part) {
    __shared__ unsigned int h[NBKT];
    __shared__ unsigned int gbase[NBKT];
    int tid = threadIdx.x, blk = blockIdx.x;
    for (int k = tid; k < NBKT; k += 512) h[k] = 0u;
    __syncthreads();
    int qbase = blk * (CHK / 4);                 // in units of 4-edge groups
    int bv[8]; unsigned int lr[8], lo[8], hiw[8]; bool val[8];
    #pragma unroll
    for (int u = 0; u < 2; u++) {
        int q = qbase + u * 512 + tid;
        bool v = (q < N_EDGES / 4);
        int4 ss = v ? src4[q] : make_int4(0, 0, 0, 0);
        int4 dd = v ? dst4[q] : make_int4(0, 0, 0, 0);
        float4 ww = v ? ew4[q] : make_float4(0.f, 0.f, 0.f, 0.f);
        int s[4] = { ss.x, ss.y, ss.z, ss.w };
        int d[4] = { dd.x, dd.y, dd.z, dd.w };
        float w[4] = { ww.x, ww.y, ww.z, ww.w };
        #pragma unroll
        for (int e = 0; e < 4; e++) {
            int i = u * 4 + e;
            val[i] = v;
            if (v) {
                int b = d[e] >> BKT_SH;
                bv[i] = b;
                lr[i] = atomicAdd(&h[b], 1u);
                lo[i] = ((unsigned int)(d[e] & (BKT_N - 1)) << 24) | (unsigned int)s[e];
                hiw[i] = __float_as_uint(w[e]);
            }
        }
    }
    __syncthreads();
    for (int k = tid; k < NBKT; k += 512) {
        unsigned int c = h[k];
        gbase[k] = c ? atomicAdd(&cursor[k], c) : 0u;
    }
    __syncthreads();
    #pragma unroll
    for (int i = 0; i < 8; i++) {
        if (!val[i]) continue;
        unsigned int off = gbase[bv[i]] + lr[i];
        if (off < SEG_CAP)  // 10-sigma margin; memory safety only
            part[(size_t)bv[i] * SEG_CAP + off] =
                ((unsigned long long)hiw[i] << 32) | lo[i];
    }
}

// ---- pass 2: per-bucket counting sort (rank-in-entry, no 2nd-pass atomics) ----
// Also emits deg/dinv, csr4 ((fp16 ew)<<16 | src), and xs[n][c] = fp16(dinv*x[n,8c..8c+7]).
__global__ void __launch_bounds__(512) k_bucket(const unsigned long long* __restrict__ part,
                                                const unsigned int* __restrict__ cursor,
                                                const float* __restrict__ x,
                                                int2* __restrict__ offs2,
                                                float* __restrict__ dinv_g,
                                                uint4* __restrict__ xs,
                                                unsigned int* __restrict__ csr4) {
    __shared__ uint2 stage[SEG_CAP];
    __shared__ unsigned int cnt[BKT_N], rowstart[BKT_N], sc[BKT_N];
    __shared__ float degf[BKT_N], dinv_l[BKT_N];
    int tid = threadIdx.x, k = blockIdx.x;
    unsigned int base = (unsigned int)k * SEG_CAP;
    unsigned int m = cursor[k];
    if (m > SEG_CAP) m = SEG_CAP;
    if (tid < BKT_N) { cnt[tid] = 0u; degf[tid] = 1.0f; }  // self loop weight
    __syncthreads();

    // histogram + rank assignment + fp32 degree
    for (unsigned int i = tid; i < m; i += 512) {
        unsigned long long p = __builtin_nontemporal_load(&part[base + i]);
        unsigned int lo = (unsigned int)p;
        unsigned int hi = (unsigned int)(p >> 32);
        unsigned int j = (lo >> 24) & (BKT_N - 1);
        unsigned int r = atomicAdd(&cnt[j], 1u);
        atomicAdd(&degf[j], __uint_as_float(hi));
        if (r > 255u) r = 255u;                 // impossible in practice; safety clamp
        stage[i] = make_uint2(lo | (r << 16), hi);   // bits[23:16] free (src < 2^16)
    }
    __syncthreads();

    // wave-0 shfl prefix scan over 128 bucket counters (inclusive)
    if (tid < 64) {
        unsigned int a = cnt[tid], b = cnt[tid + 64];
        unsigned int sa = a;
        #pragma unroll
        for (int off = 1; off < 64; off <<= 1) {
            unsigned int tv = __shfl_up(sa, off);
            if ((tid & 63) >= off) sa += tv;
        }
        unsigned int tot = __shfl(sa, 63);
        unsigned int sb = b;
        #pragma unroll
        for (int off = 1; off < 64; off <<= 1) {
            unsigned int tv = __shfl_up(sb, off);
            if ((tid & 63) >= off) sb += tv;
        }
        sc[tid] = sa;
        sc[tid + 64] = sb + tot;
    }
    __syncthreads();

    int n0 = k * BKT_N;
    int nn = N_NODES - n0; if (nn > BKT_N) nn = BKT_N;

    if (tid < BKT_N) {
        unsigned int rs = sc[tid] - cnt[tid];
        rowstart[tid] = rs;
        float dv = rsqrtf(degf[tid]);
        dinv_l[tid] = dv;
        if (tid < nn) {
            dinv_g[n0 + tid] = dv;
            offs2[n0 + tid] = make_int2((int)(base + rs), (int)(base + sc[tid]));
        }
    }
    __syncthreads();

    // sorted write-out: slot = rowstart[j] + stored rank (no atomics)
    for (unsigned int i = tid; i < m; i += 512) {
        uint2 vv = stage[i];
        unsigned int j = (vv.x >> 24) & (BKT_N - 1);
        unsigned int r = (vv.x >> 16) & 0xFFu;
        __half hw = __float2half(__uint_as_float(vv.y));
        unsigned int entry = ((unsigned int)__half_as_ushort(hw) << 16) |
                             (vv.x & 0xFFFFu);
        csr4[base + rowstart[j] + r] = entry;
    }

    // xs[n*6+c] = fp16(dinv[n] * x[n, 8c..8c+7])  (coalesced uint4)
    for (int idx = tid; idx < nn * 6; idx += 512) {
        int j = idx / 6, c = idx % 6;
        float di = dinv_l[j];
        const float4* xr = (const float4*)(x + (size_t)(n0 + j) * FP + c * 8);
        float4 a = xr[0], b = xr[1];
        __half2 h0 = __floats2half2_rn(di * a.x, di * a.y);
        __half2 h1 = __floats2half2_rn(di * a.z, di * a.w);
        __half2 h2 = __floats2half2_rn(di * b.x, di * b.y);
        __half2 h3 = __floats2half2_rn(di * b.z, di * b.w);
        uint4 o;
        o.x = *(unsigned int*)&h0; o.y = *(unsigned int*)&h1;
        o.z = *(unsigned int*)&h2; o.w = *(unsigned int*)&h3;
        xs[(size_t)(n0 + j) * 6 + c] = o;
    }
}

// ---- pass 3: FUSED gather + epilogue. 192 threads = 8 nodes x 24 lanes ----
// Gather: 6 feature-chunks x 4 edge-groups per node (round-3 structure).
// Epilogue: cooperative 24-lane per node via LDS (phases A/B/C), replacing
// the separate low-occupancy k_node (46us, VALUBusy 0.3% — boundary-flush tax).
__global__ void __launch_bounds__(192) k_gnode(const uint4* __restrict__ xs,
                                               const float* __restrict__ dinv,
                                               const int2* __restrict__ offs2,
                                               const unsigned int* __restrict__ csr4,
                                               const float* __restrict__ att,
                                               const float* __restrict__ Wz,
                                               const float* __restrict__ bz,
                                               const float* __restrict__ Wh,
                                               const float* __restrict__ bh,
                                               const float* __restrict__ lzW,
                                               const float* __restrict__ lzb,
                                               const float* __restrict__ lhW,
                                               const float* __restrict__ lhb,
                                               const float* __restrict__ linW,
                                               const float* __restrict__ linb,
                                               float* __restrict__ out) {
    __shared__ float row[8][48];     // aggregated features, f-major (f*6+p)
    __shared__ float gzs[8][72];     // gz(p,kk) per node
    __shared__ float ghs[8][72];     // gh(p,kk) per node
    __shared__ float Hl[8][12];      // relu(H[j]) per node

    int tid = threadIdx.x;
    int L = tid / 24, r = tid % 24, c = r >> 2, g = r & 3;
    int n = blockIdx.x * 8 + L;      // 50000 = 6250 * 8, no tail

    // ---- gather phase (identical math to round-3 k_gather) ----
    int2 oe = offs2[n];
    const unsigned int* rowp = csr4 + oe.x;
    int cnt = oe.y - oe.x;
    float a0 = 0.f, a1 = 0.f, a2 = 0.f, a3 = 0.f;
    float a4 = 0.f, a5 = 0.f, a6 = 0.f, a7 = 0.f;
    int kk = 0;
    for (; kk + 16 <= cnt; kk += 16) {
        unsigned int p[4]; uint4 v[4];
        #pragma unroll
        for (int u = 0; u < 4; u++)
            p[u] = __builtin_nontemporal_load(rowp + kk + 4 * u + g);
        #pragma unroll
        for (int u = 0; u < 4; u++)
            v[u] = xs[(size_t)(p[u] & 0xFFFFu) * 6 + c];
        #pragma unroll
        for (int u = 0; u < 4; u++) {
            float w = __half2float(__ushort_as_half((unsigned short)(p[u] >> 16)));
            float2 e0 = __half22float2(*(__half2*)&v[u].x);
            float2 e1 = __half22float2(*(__half2*)&v[u].y);
            float2 e2 = __half22float2(*(__half2*)&v[u].z);
            float2 e3 = __half22float2(*(__half2*)&v[u].w);
            a0 += w * e0.x; a1 += w * e0.y; a2 += w * e1.x; a3 += w * e1.y;
            a4 += w * e2.x; a5 += w * e2.y; a6 += w * e3.x; a7 += w * e3.y;
        }
    }
    for (int jj = kk + g; jj < cnt; jj += 4) {
        unsigned int p = __builtin_nontemporal_load(rowp + jj);
        float w = __half2float(__ushort_as_half((unsigned short)(p >> 16)));
        uint4 v = xs[(size_t)(p & 0xFFFFu) * 6 + c];
        float2 e0 = __half22float2(*(__half2*)&v.x);
        float2 e1 = __half22float2(*(__half2*)&v.y);
        float2 e2 = __half22float2(*(__half2*)&v.z);
        float2 e3 = __half22float2(*(__half2*)&v.w);
        a0 += w * e0.x; a1 += w * e0.y; a2 += w * e1.x; a3 += w * e1.y;
        a4 += w * e2.x; a5 += w * e2.y; a6 += w * e3.x; a7 += w * e3.y;
    }
    // combine the 4 edge-groups (partners t^1, t^2: 4-blocks are 4-aligned,
    // never straddle a wave: tid = L*24 + c*4 + g)
    a0 += __shfl_xor(a0, 1); a1 += __shfl_xor(a1, 1);
    a2 += __shfl_xor(a2, 1); a3 += __shfl_xor(a3, 1);
    a4 += __shfl_xor(a4, 1); a5 += __shfl_xor(a5, 1);
    a6 += __shfl_xor(a6, 1); a7 += __shfl_xor(a7, 1);
    a0 += __shfl_xor(a0, 2); a1 += __shfl_xor(a1, 2);
    a2 += __shfl_xor(a2, 2); a3 += __shfl_xor(a3, 2);
    a4 += __shfl_xor(a4, 2); a5 += __shfl_xor(a5, 2);
    a6 += __shfl_xor(a6, 2); a7 += __shfl_xor(a7, 2);
    if (g == 0) {
        uint4 sf = xs[(size_t)n * 6 + c];      // self loop (dinv[n]*x already folded)
        float2 s0 = __half22float2(*(__half2*)&sf.x);
        float2 s1 = __half22float2(*(__half2*)&sf.y);
        float2 s2 = __half22float2(*(__half2*)&sf.z);
        float2 s3 = __half22float2(*(__half2*)&sf.w);
        float di = dinv[n];
        row[L][8 * c + 0] = di * (a0 + s0.x); row[L][8 * c + 1] = di * (a1 + s0.y);
        row[L][8 * c + 2] = di * (a2 + s1.x); row[L][8 * c + 3] = di * (a3 + s1.y);
        row[L][8 * c + 4] = di * (a4 + s2.x); row[L][8 * c + 5] = di * (a5 + s2.y);
        row[L][8 * c + 6] = di * (a6 + s3.x); row[L][8 * c + 7] = di * (a7 + s3.y);
    }
    __syncthreads();

    // ---- phase A: gz/gh(p,kk) = b[kk] + sum_f row[f*6+p] * W[f*12+kk] ----
    for (int it = r; it < 72; it += 24) {
        int p = it / 12, q = it - p * 12;
        float gz = bz[q], gh = bh[q];
        #pragma unroll
        for (int f = 0; f < F_IN; f++) {
            float xv = row[L][f * 6 + p];
            gz += xv * Wz[f * F_OUT + q];
            gh += xv * Wh[f * F_OUT + q];
        }
        gzs[L][it] = gz; ghs[L][it] = gh;
    }
    __syncthreads();

    // ---- phase B: 12 j-lanes/node: H[j] over 6 periods ----
    if (r < 12) {
        // softmax(att) — tiny, recomputed per lane
        float a[PERIODS];
        float mx = -1e30f;
        #pragma unroll
        for (int p = 0; p < PERIODS; p++) { a[p] = att[p]; mx = fmaxf(mx, a[p]); }
        float se = 0.f;
        #pragma unroll
        for (int p = 0; p < PERIODS; p++) { a[p] = __expf(a[p] - mx); se += a[p]; }
        float inv = 1.f / se;
        int j = r;
        float hacc = 0.f;
        #pragma unroll
        for (int p = 0; p < PERIODS; p++) {
            float z = lzb[j], t2 = lhb[j];
            #pragma unroll
            for (int q = 0; q < F_OUT; q++) {
                z  += gzs[L][p * 12 + q] * lzW[j * (2 * F_OUT) + q];
                t2 += ghs[L][p * 12 + q] * lhW[j * (2 * F_OUT) + q];
            }
            float Z = 1.f / (1.f + __expf(-z));
            // fast tanh: 1 - 2/(e^{2x}+1); saturates correctly for |x| large
            float e2 = __expf(2.f * t2);
            float th = 1.f - __fdividef(2.f, e2 + 1.f);
            hacc += (a[p] * inv) * (1.f - Z) * th;
        }
        Hl[L][j] = fmaxf(hacc, 0.f);           // relu fused here
    }
    __syncthreads();

    // ---- phase C: 6 q-lanes/node: out = linb + relu(H) @ linW^T ----
    if (r < PERIODS) {
        float acc = linb[r];
        #pragma unroll
        for (int j = 0; j < F_OUT; j++)
            acc += Hl[L][j] * linW[r * F_OUT + j];
        out[(size_t)n * PERIODS + r] = acc;
    }
}

extern "C" void kernel_launch(void* const* d_in, const int* in_sizes, int n_in,
                              void* d_out, int out_size, void* d_ws, size_t ws_size,
                              hipStream_t stream) {
    const float* x    = (const float*)d_in[0];
    const int*   ei   = (const int*)d_in[1];
    const float* ew   = (const float*)d_in[2];
    const float* att  = (const float*)d_in[3];
    const float* Wz   = (const float*)d_in[4];
    const float* bz   = (const float*)d_in[5];
    // d_in[6]=Wr, d_in[7]=br : dead (H0 == 0)
    const float* Wh   = (const float*)d_in[8];
    const float* bh   = (const float*)d_in[9];
    const float* lzW  = (const float*)d_in[10];
    const float* lzb  = (const float*)d_in[11];
    // d_in[12]=lrW, d_in[13]=lrb : dead
    const float* lhW  = (const float*)d_in[14];
    const float* lhb  = (const float*)d_in[15];
    const float* linW = (const float*)d_in[16];
    const float* linb = (const float*)d_in[17];
    float* out = (float*)d_out;

    // ws layout (~27.7 MB): xs (16B-aligned first), part, csr4, offs2, dinv, cursor
    uint4* xs   = (uint4*)d_ws;                                   // N*6 uint4 = 4.8 MB
    unsigned long long* part = (unsigned long long*)(xs + (size_t)N_NODES * 6);   // 14.8 MB
    unsigned int* csr4 = (unsigned int*)(part + (size_t)NBKT * SEG_CAP);          // 7.4 MB
    int2*  offs2 = (int2*)(csr4 + (size_t)NBKT * SEG_CAP);        // N int2
    float* dinv  = (float*)(offs2 + N_NODES);                     // N f32
    unsigned int* cursor = (unsigned int*)(dinv + N_NODES);       // NBKT u32

    const int* srcp = ei;
    const int* dstp = ei + N_EDGES;

    k_zero<<<1, 512, 0, stream>>>(cursor);
    k_scatter<<<NCHK, 512, 0, stream>>>((const int4*)srcp, (const int4*)dstp,
                                        (const float4*)ew, cursor, part);
    k_bucket<<<NBKT, 512, 0, stream>>>(part, cursor, x, offs2, dinv, xs, csr4);
    k_gnode<<<N_NODES / 8, 192, 0, stream>>>(xs, dinv, offs2, csr4, att,
                                             Wz, bz, Wh, bh, lzW, lzb, lhW, lhb,
                                             linW, linb, out);
}